// Round 3
// baseline (10344.797 us; speedup 1.0000x reference)
//
#include <hip/hip_runtime.h>

#define B_ 256
#define T_ 512
#define V_ 128
#define E_ 128
#define H_ 256
#define FH 1024

#define GROUPS 16
#define RPG 16     // batch rows per group
#define CWG 16     // column-WGs per group
#define NWG (GROUPS*CWG)   // 256 = 1 block/CU

#define GBLK 272   // floats per (grp,c) publish block (4*68, padded for proj banks)
#define HLAY (2*GROUPS*CWG*GBLK)   // one layer, both bufs = 139264 floats

typedef float f4 __attribute__((ext_vector_type(4)));

// ---- workspace layout (float offsets) ----
#define OFF_HT0  0                              // h0 [2buf][grp][c][GBLK]
#define OFF_HT1  (OFF_HT0 + HLAY)
#define OFF_BAR  (OFF_HT1 + HLAY)               // 16 groups * 128 uints
#define BARSZ    (GROUPS*128)
#define OFF_TP   (OFF_BAR + BARSZ)              // TokProj [V][1024] packed
#define OFF_CP   (OFF_TP + V_*FH)               // ClusProj [B][1024] packed (+b0)
#define OFF_WP0  (OFF_CP + B_*FH)               // W0h x4-packed [16c][64kb][64lane][4j]
#define OFF_WP1  (OFF_WP0 + CWG*64*64*4)        // W1  x4-packed [16c][128kb][64lane][4j]
#define OFF_DWT  (OFF_WP1 + CWG*128*64*4)       // decoderW^T [128v][256k]
#define OFF_B1   (OFF_DWT + V_*H_)              // b1 packed [1024]

// packed column order: local col = u*4+g  ->  global z-col G = g*256 + c*16 + u
__device__ __forceinline__ int gcol(int c, int col) {
  int u = col >> 2, g = col & 3;
  return g*256 + c*16 + u;
}

__device__ __forceinline__ float sigm(float x){ return 1.f/(1.f+__expf(-x)); }
__device__ __forceinline__ float tanh_(float x){ return 1.f - 2.f/(1.f+__expf(2.f*x)); }

// ============ prep kernels ============

__global__ void prep_pack(const float* __restrict__ W0, const float* __restrict__ W1,
                          const float* __restrict__ dW, const float* __restrict__ b1,
                          float* __restrict__ ws) {
  float* wp0 = ws + OFF_WP0; float* wp1 = ws + OFF_WP1;
  float* dwT = ws + OFF_DWT; float* b1p = ws + OFF_B1;
  const int N0 = CWG*64*64*4;     // 262144
  const int N1 = CWG*128*64*4;    // 524288
  const int N2 = V_*H_;           // 32768
  const int N3 = FH;              // 1024
  const int total = N0+N1+N2+N3;
  for (int i = blockIdx.x*blockDim.x + threadIdx.x; i < total; i += gridDim.x*blockDim.x) {
    if (i < N0) {
      int cc = i >> 14; int rem = i & 16383;
      int kb = rem >> 8; int ln = (rem >> 2) & 63; int j = i & 3;
      int k = kb*4 + j;
      wp0[i] = W0[(E_+H_+k)*FH + gcol(cc, ln)];          // W0 h0-rows
    } else if (i < N0+N1) {
      int idx = i - N0;
      int cc = idx >> 15; int rem = idx & 32767;
      int kb = rem >> 8; int ln = (rem >> 2) & 63; int j = idx & 3;
      int k2 = kb*4 + j;                                  // 0..255 h0n, 256..511 h1
      wp1[idx] = W1[k2*FH + gcol(cc, ln)];
    } else if (i < N0+N1+N2) {
      int l = i - N0 - N1;
      int v = l >> 8, k = l & 255;
      dwT[l] = dW[k*V_ + v];
    } else {
      int cc2 = i - N0 - N1 - N2;
      b1p[cc2] = b1[gcol(cc2>>6, cc2&63)];
    }
  }
}

__global__ void prep_tok(const float* __restrict__ cemb, const float* __restrict__ W0,
                         float* __restrict__ ws) {
  __shared__ float ce[E_];
  float* TP = ws + OFF_TP;
  int v = blockIdx.x >> 2, q = blockIdx.x & 3;
  int tid = threadIdx.x;
  if (tid < E_) ce[tid] = cemb[v*E_ + tid];
  __syncthreads();
  int ccol = q*256 + tid;
  int G = gcol(ccol>>6, ccol&63);
  float acc = 0.f;
  for (int e = 0; e < E_; ++e) acc = fmaf(ce[e], W0[e*FH + G], acc);
  TP[v*FH + ccol] = acc;
}

__global__ void prep_clus(const int* __restrict__ clus, const float* __restrict__ clemb,
                          const float* __restrict__ W0, const float* __restrict__ b0,
                          float* __restrict__ ws) {
  __shared__ float ce[H_];
  float* CP = ws + OFF_CP;
  int b = blockIdx.x >> 2, q = blockIdx.x & 3;
  int tid = threadIdx.x;
  int cl = clus[b];
  ce[tid] = clemb[(long long)cl*H_ + tid];
  __syncthreads();
  int ccol = q*256 + tid;
  int G = gcol(ccol>>6, ccol&63);
  float acc = b0[G];
  for (int e = 0; e < H_; ++e) acc = fmaf(ce[e], W0[(E_+e)*FH + G], acc);
  CP[b*FH + ccol] = acc;
}

// ============ sync & staging primitives ============

__device__ __forceinline__ void st64(float* p, float a, float b) {
  float2 t; t.x = a; t.y = b;
  __hip_atomic_store((unsigned long long*)p, __builtin_bit_cast(unsigned long long, t),
                     __ATOMIC_RELAXED, __HIP_MEMORY_SCOPE_AGENT);
}

__device__ __forceinline__ unsigned long long ld64(const void* p) {
  return __hip_atomic_load((const unsigned long long*)p, __ATOMIC_RELAXED,
                           __HIP_MEMORY_SCOPE_AGENT);
}

// relaxed flag publish ordered by explicit vmcnt drain (no wbl2 on the path)
__device__ __forceinline__ void flag_set(unsigned* p, unsigned v) {
  asm volatile("s_waitcnt vmcnt(0)" ::: "memory");
  __hip_atomic_store(p, v, __ATOMIC_RELAXED, __HIP_MEMORY_SCOPE_AGENT);
}

// wave-0-only poll of BOTH flag lines (fA via lanes 0-31, fB via lanes 32-63)
__device__ __forceinline__ void spinAB(const unsigned* fA, const unsigned* fB,
                                       int lane, unsigned tgt) {
  const unsigned* p = ((lane < 32) ? fA : fB) + (lane & 15);
  unsigned v = __hip_atomic_load(p, __ATOMIC_RELAXED, __HIP_MEMORY_SCOPE_AGENT);
  while (!__all((int)(v >= tgt))) {
    __builtin_amdgcn_s_sleep(2);
    v = __hip_atomic_load(p, __ATOMIC_RELAXED, __HIP_MEMORY_SCOPE_AGENT);
  }
}

// single-line poll (epilogue, fB only)
__device__ __forceinline__ void spin1(const unsigned* f, int lane, unsigned tgt) {
  const unsigned* p = f + (lane & 15);
  unsigned v = __hip_atomic_load(p, __ATOMIC_RELAXED, __HIP_MEMORY_SCOPE_AGENT);
  while (!__all((int)(v >= tgt))) {
    __builtin_amdgcn_s_sleep(2);
    v = __hip_atomic_load(p, __ATOMIC_RELAXED, __HIP_MEMORY_SCOPE_AGENT);
  }
}

// ============ main persistent kernel ============
//
// RPG=16, 16 groups x 16 column-WGs = 256 WGs (1 block/CU). Merged
// single-exchange schedule: buf(t&1) holds {H0(t), H1(t-1)}, flags >= t+1.
// Gate/publish row permutation: lane l = q*16+gu (q=l>>4) owns rows
// {q, q+4, q+8, q+12} of unit gu; publish block per (grp,c) is
// [4q][68: 16 units x 4 rows + 4 pad] -> one contiguous ~1KB wave store.
// Stage = linear 32KB copy; matvec h-reads are wave-uniform LDS broadcasts
// (layout-free); proj reads the q-strided f4 rows (pad 68 keeps banks clean).
// z0 partials (za) overlay the h0 staging region (dead after matvec) to keep
// static LDS under 64KB.

__global__ __launch_bounds__(256, 1) void lstm_persist(
    const int* __restrict__ toks, const int* __restrict__ lens,
    const float* __restrict__ decB, float* __restrict__ ws, float* __restrict__ out)
{
  // swizzle: xcd = blk&7 hosts groups {2*xcd, 2*xcd+1}; all 16 c per XCD.
  const int blk  = blockIdx.x;
  const int grp  = (blk & 7)*2 + ((blk >> 3) & 1);   // 0..15
  const int c    = blk >> 4;                          // column-WG 0..15
  const int tid  = threadIdx.x;
  const int lane = tid & 63;
  const int wv   = tid >> 6;
  const int cof  = c*64;
  const int gbase = grp*RPG;

  float* ht0 = ws + OFF_HT0;
  float* ht1 = ws + OFF_HT1;
  unsigned* fgrp = (unsigned*)(ws + OFF_BAR) + grp*128;
  unsigned* fA = fgrp;            // 16 slots (one 64B line)
  unsigned* fB = fgrp + 32;       // 16 slots
  const float* TP   = ws + OFF_TP;
  const float* CP   = ws + OFF_CP;
  const float* wp0c = ws + OFF_WP0 + c*(64*64*4);
  const float* wp1c = ws + OFF_WP1 + c*(128*64*4);
  const float* dwT  = ws + OFF_DWT;
  const float* b1p  = ws + OFF_B1;

  __shared__ __align__(16) float lds_h[8704];   // [h0: 16c x 272][h1: same] staged
  __shared__ __align__(16) float zbS[4][16][64];// z1 partials [wave][row][col]
  __shared__ float ldsW[8][260];                // decoderW slice [v][k]
  __shared__ __align__(16) f4 predS[8][32];     // proj partials [kslice][q*8+v]
  float* zaP = lds_h;                           // z0 partials overlay h0 region

  // stage decoder weight slice (v = c*8 .. c*8+7)
  for (int i = tid; i < 8*H_; i += 256)
    ldsW[i>>8][i&255] = dwT[(c*8 + (i>>8))*H_ + (i&255)];

  // ---- group max length (all lanes) ----
  int Lg = lens[gbase + (lane & 15)];
  Lg = max(Lg, __shfl_xor(Lg, 1));
  Lg = max(Lg, __shfl_xor(Lg, 2));
  Lg = max(Lg, __shfl_xor(Lg, 4));
  Lg = max(Lg, __shfl_xor(Lg, 8));

  // ---- gate-lane constants (wave0 = layer0, wave1 = layer1) ----
  const int gu = lane & 15, q = lane >> 4;   // unit 0..15, q-row 0..3
  int lenR[4]; const int* tokPt[4]; f4 cpR[4];
  #pragma unroll
  for (int m = 0; m < 4; ++m) {
    const int row = gbase + q + 4*m;
    lenR[m]  = lens[row];
    tokPt[m] = toks + row*T_;
    cpR[m]   = *(const f4*)(CP + row*FH + cof + gu*4);
  }
  const f4 b1v = *(const f4*)(b1p + cof + gu*4);
  float c0s[4] = {0,0,0,0}, h0r[4] = {0,0,0,0};   // wave0 L0 state (rows q+4m)
  float c1s[4] = {0,0,0,0}, h1r[4] = {0,0,0,0};   // wave1 L1 state

  // ---- projection constants ----
  const int pv = lane & 7, pq = (lane >> 3) & 3, ph = lane >> 5;
  const int slice = wv*2 + ph;                     // k-slice 0..7 (32 k each)
  const float decb = decB[c*8 + pv];
  int plenR[4]; size_t obase[4];
  #pragma unroll
  for (int m = 0; m < 4; ++m) {
    const int row = gbase + pq + 4*m;
    plenR[m] = lens[row];
    obase[m] = (size_t)row*T_*V_ + c*8 + pv;
  }

  __syncthreads();   // ldsW staged

  // ---- prologue: H0(0) from TP+CP; H1(-1)=0 via pre-zeroed ws ----
  if (wv == 0) {
    #pragma unroll
    for (int m = 0; m < 4; ++m) {
      f4 z = *(const f4*)(TP + tokPt[m][0]*FH + cof + gu*4) + cpR[m];
      float ci = sigm(z.x), cj = tanh_(z.y), cf = sigm(z.z + 1.f), co = sigm(z.w);
      float cn = fmaf(c0s[m], cf, ci*cj), hn = tanh_(cn)*co;
      if (0 < lenR[m]) { c0s[m] = cn; h0r[m] = hn; }
    }
    float* pb = ht0 + ((size_t)(0*GROUPS + grp)*CWG + c)*GBLK + q*68 + gu*4;
    st64(pb,     h0r[0], h0r[1]);
    st64(pb + 2, h0r[2], h0r[3]);
    if (lane == 0) flag_set(fA + c, 1u);
  } else if (wv == 1) {
    if (lane == 0) flag_set(fB + c, 1u);   // h1 buf0 pre-zeroed by memset
  }

  for (int t = 0; t < Lg; ++t) {
    const int buf = t & 1;

    // TP prefetch for next-step z0 (issued before the spin; in flight during it)
    f4 tpR[4];
    if (wv == 0 && t + 1 < Lg) {
      #pragma unroll
      for (int m = 0; m < 4; ++m)
        tpR[m] = *(const f4*)(TP + tokPt[m][t+1]*FH + cof + gu*4);
    }

    // ---- single wait per step: {H0(t), H1(t-1)} both ready ----
    if (wv == 0) spinAB(fA, fB, lane, (unsigned)(t + 1));
    __syncthreads();                                   // (1)
    __atomic_signal_fence(__ATOMIC_SEQ_CST);

    // ---- stage both layers -> LDS (linear coalesced copy, 2x 2176 u64) ----
    {
      const unsigned long long* sA =
        (const unsigned long long*)(ht0 + (size_t)(buf*GROUPS + grp)*CWG*GBLK);
      const unsigned long long* sB =
        (const unsigned long long*)(ht1 + (size_t)(buf*GROUPS + grp)*CWG*GBLK);
      #pragma unroll
      for (int i = 0; i < 17; ++i) {
        const int o = tid + i*256;                     // 0..4351
        const unsigned long long* s = (o < 2176) ? (sA + o) : (sB + (o - 2176));
        unsigned long long d = ld64(s);
        *(unsigned long long*)&lds_h[o*2] = d;
      }
    }
    __syncthreads();                                   // (2)

    // ---- fused matvec: A0 = W0h*h0; A1 = W1lo*h0 + W1up*h1 (f4 over rows) ----
    f4 A0[4], A1[4];
    #pragma unroll
    for (int r = 0; r < 4; ++r) { A0[r] = (f4){0,0,0,0}; A1[r] = (f4){0,0,0,0}; }
    #pragma unroll 2
    for (int b = 0; b < 16; ++b) {
      const int kb = wv*16 + b;
      const f4 w0 = *(const f4*)(wp0c + kb*256 + lane*4);
      const f4 wl = *(const f4*)(wp1c + kb*256 + lane*4);
      const f4 wu = *(const f4*)(wp1c + (64 + kb)*256 + lane*4);
      #pragma unroll
      for (int j = 0; j < 4; ++j) {
        const int k = kb*4 + j;
        const float* hb = lds_h + (k >> 4)*GBLK + (k & 15)*4;
        const float w0j = w0[j], wlj = wl[j], wuj = wu[j];
        #pragma unroll
        for (int q2 = 0; q2 < 4; ++q2) {
          const f4 h0q = *(const f4*)(hb + q2*68);          // uniform broadcast
          const f4 h1q = *(const f4*)(hb + 4352 + q2*68);
          A0[q2] += w0j * h0q;
          A1[q2] += wlj * h0q + wuj * h1q;
        }
      }
    }

    // ---- projection partial over this lane's 32-k slice (h1 = H1(t-1)) ----
    f4 pacc = (f4){0,0,0,0};
    {
      const float* h1b = lds_h + 4352;
      #pragma unroll 4
      for (int k2 = 0; k2 < 32; ++k2) {
        const int k = slice*32 + k2;
        const f4 hv = *(const f4*)(h1b + (k >> 4)*GBLK + pq*68 + (k & 15)*4);
        pacc += ldsW[pv][k] * hv;
      }
    }

    __syncthreads();               // (2.5) protect h0 overlay before za writes

    #pragma unroll
    for (int q2 = 0; q2 < 4; ++q2)
      #pragma unroll
      for (int m = 0; m < 4; ++m) {
        zaP[(wv*16 + q2 + 4*m)*64 + lane] = A0[q2][m];
        zbS[wv][q2 + 4*m][lane]           = A1[q2][m];
      }
    predS[slice][pq*8 + pv] = pacc;
    __syncthreads();                                   // (3)

    if (wv == 0) {
      // gates L0 -> H0(t+1), publish to buf^1
      if (t + 1 < Lg) {
        #pragma unroll
        for (int m = 0; m < 4; ++m) {
          const int row = q + 4*m;
          f4 z = *(const f4*)&zaP[(0*16 + row)*64 + gu*4];
          z += *(const f4*)&zaP[(1*16 + row)*64 + gu*4];
          z += *(const f4*)&zaP[(2*16 + row)*64 + gu*4];
          z += *(const f4*)&zaP[(3*16 + row)*64 + gu*4];
          z += tpR[m] + cpR[m];
          float ci = sigm(z.x), cj = tanh_(z.y), cf = sigm(z.z + 1.f), co = sigm(z.w);
          float cn = fmaf(c0s[m], cf, ci*cj), hn = tanh_(cn)*co;
          if (t + 1 < lenR[m]) { c0s[m] = cn; h0r[m] = hn; }
        }
        float* pb = ht0 + ((size_t)((buf^1)*GROUPS + grp)*CWG + c)*GBLK + q*68 + gu*4;
        st64(pb,     h0r[0], h0r[1]);
        st64(pb + 2, h0r[2], h0r[3]);
        if (lane == 0) flag_set(fA + c, (unsigned)(t + 2));
      }
    } else if (wv == 1) {
      // gates L1 -> H1(t), publish to buf^1
      #pragma unroll
      for (int m = 0; m < 4; ++m) {
        const int row = q + 4*m;
        f4 z = *(const f4*)&zbS[0][row][gu*4];
        z += *(const f4*)&zbS[1][row][gu*4];
        z += *(const f4*)&zbS[2][row][gu*4];
        z += *(const f4*)&zbS[3][row][gu*4];
        z += b1v;
        float ci = sigm(z.x), cj = tanh_(z.y), cf = sigm(z.z + 1.f), co = sigm(z.w);
        float cn = fmaf(c1s[m], cf, ci*cj), hn = tanh_(cn)*co;
        if (t < lenR[m]) { c1s[m] = cn; h1r[m] = hn; }
      }
      float* pb = ht1 + ((size_t)((buf^1)*GROUPS + grp)*CWG + c)*GBLK + q*68 + gu*4;
      st64(pb,     h1r[0], h1r[1]);
      st64(pb + 2, h1r[2], h1r[3]);
      if (lane == 0) flag_set(fB + c, (unsigned)(t + 2));
    } else if (wv == 2) {
      // out(t-1) from this iteration's pred (computed from H1(t-1))
      if (t > 0 && lane < 32) {
        f4 tot = predS[0][lane];
        #pragma unroll
        for (int s = 1; s < 8; ++s) tot += predS[s][lane];
        #pragma unroll
        for (int m = 0; m < 4; ++m)
          if (t - 1 < plenR[m]) out[obase[m] + (size_t)(t-1)*V_] = tot[m] + decb;
      }
    }
  }

  // ---- epilogue: out(Lg-1) from H1(Lg-1) in buf (Lg&1), fB reaches Lg+1 ----
  if (wv == 0) spin1(fB, lane, (unsigned)(Lg + 1));
  __syncthreads();
  __atomic_signal_fence(__ATOMIC_SEQ_CST);
  {
    const unsigned long long* sB =
      (const unsigned long long*)(ht1 + (size_t)((Lg & 1)*GROUPS + grp)*CWG*GBLK);
    #pragma unroll
    for (int i = 0; i < 9; ++i) {
      const int o = tid + i*256;
      if (o < 2176) *(unsigned long long*)&lds_h[4352 + o*2] = ld64(sB + o);
    }
  }
  __syncthreads();
  {
    f4 pacc = (f4){0,0,0,0};
    const float* h1b = lds_h + 4352;
    #pragma unroll 4
    for (int k2 = 0; k2 < 32; ++k2) {
      const int k = slice*32 + k2;
      const f4 hv = *(const f4*)(h1b + (k >> 4)*GBLK + pq*68 + (k & 15)*4);
      pacc += ldsW[pv][k] * hv;
    }
    predS[slice][pq*8 + pv] = pacc;
  }
  __syncthreads();
  if (wv == 2 && lane < 32) {
    f4 tot = predS[0][lane];
    #pragma unroll
    for (int s = 1; s < 8; ++s) tot += predS[s][lane];
    #pragma unroll
    for (int m = 0; m < 4; ++m)
      if (Lg - 1 < plenR[m]) out[obase[m] + (size_t)(Lg-1)*V_] = tot[m] + decb;
  }
}

// ============ launch ============

extern "C" void kernel_launch(void* const* d_in, const int* in_sizes, int n_in,
                              void* d_out, int out_size, void* d_ws, size_t ws_size,
                              hipStream_t stream) {
  const int*   toks  = (const int*)d_in[0];
  const int*   lens  = (const int*)d_in[1];
  const int*   clus  = (const int*)d_in[2];
  const float* cemb  = (const float*)d_in[3];
  const float* clemb = (const float*)d_in[4];
  const float* W0    = (const float*)d_in[5];
  const float* b0    = (const float*)d_in[6];
  const float* W1    = (const float*)d_in[7];
  const float* b1    = (const float*)d_in[8];
  const float* dW    = (const float*)d_in[9];
  const float* decB  = (const float*)d_in[10];
  float* out = (float*)d_out;
  float* ws  = (float*)d_ws;

  // zero output (masked positions must be exactly 0), h buffers (H1(-1)=0),
  // and the flag block
  hipMemsetAsync(out, 0, (size_t)B_*T_*V_*sizeof(float), stream);
  hipMemsetAsync(ws, 0, (size_t)(OFF_BAR + BARSZ)*sizeof(float), stream);

  prep_pack<<<1024, 256, 0, stream>>>(W0, W1, dW, b1, ws);
  prep_tok <<<V_*4, 256, 0, stream>>>(cemb, W0, ws);
  prep_clus<<<B_*4, 256, 0, stream>>>(clus, clemb, W0, b0, ws);
  lstm_persist<<<NWG, 256, 0, stream>>>(toks, lens, decB, ws, out);
}

// Round 4
// 5420.794 us; speedup vs baseline: 1.9084x; 1.9084x over previous
//
#include <hip/hip_runtime.h>

#define B_ 256
#define T_ 512
#define V_ 128
#define E_ 128
#define H_ 256
#define FH 1024

#define GROUPS 32
#define RPG 8      // batch rows per group
#define CWG 16     // column-WGs per group
#define NWG (GROUPS*CWG)   // 512 = 2 blocks/CU

#define HTG 2048   // floats: one group's h, one layer, one buffer ([16c][16gu][8 r'])
#define GST (GROUPS*HTG)   // 65536

typedef float f4 __attribute__((ext_vector_type(4)));

// ---- workspace layout (float offsets) ----
#define OFF_HT0  0                              // h0 [2buf][grp][c][gu][r']
#define OFF_HT1  (OFF_HT0 + 2*GST)
#define OFF_BAR  (OFF_HT1 + 2*GST)              // 32 groups * 1024 uints (4KB/grp)
#define BARSZ    (GROUPS*1024)                  // fA_c at [c*32], fB_c at [c*32+16]
#define OFF_TP   (OFF_BAR + BARSZ)              // TokProj [V][1024] packed
#define OFF_CP   (OFF_TP + V_*FH)               // ClusProj [B][1024] packed (+b0)
#define OFF_WP0  (OFF_CP + B_*FH)               // W0h x4-packed [16c][64kb][64lane][4j]
#define OFF_WP1  (OFF_WP0 + CWG*64*64*4)        // W1  x4-packed [16c][128kb][64lane][4j]
#define OFF_DWT  (OFF_WP1 + CWG*128*64*4)       // decoderW^T [128v][256k]
#define OFF_B1   (OFF_DWT + V_*H_)              // b1 packed [1024]

// packed column order: local col = u*4+g  ->  global z-col G = g*256 + c*16 + u
__device__ __forceinline__ int gcol(int c, int col) {
  int u = col >> 2, g = col & 3;
  return g*256 + c*16 + u;
}

__device__ __forceinline__ float sigm(float x){ return 1.f/(1.f+__expf(-x)); }
__device__ __forceinline__ float tanh_(float x){ return 1.f - 2.f/(1.f+__expf(2.f*x)); }

// ============ prep kernels ============

__global__ void prep_pack(const float* __restrict__ W0, const float* __restrict__ W1,
                          const float* __restrict__ dW, const float* __restrict__ b1,
                          float* __restrict__ ws) {
  float* wp0 = ws + OFF_WP0; float* wp1 = ws + OFF_WP1;
  float* dwT = ws + OFF_DWT; float* b1p = ws + OFF_B1;
  const int N0 = CWG*64*64*4;     // 262144
  const int N1 = CWG*128*64*4;    // 524288
  const int N2 = V_*H_;           // 32768
  const int N3 = FH;              // 1024
  const int total = N0+N1+N2+N3;
  for (int i = blockIdx.x*blockDim.x + threadIdx.x; i < total; i += gridDim.x*blockDim.x) {
    if (i < N0) {
      int cc = i >> 14; int rem = i & 16383;
      int kb = rem >> 8; int ln = (rem >> 2) & 63; int j = i & 3;
      int k = kb*4 + j;
      wp0[i] = W0[(E_+H_+k)*FH + gcol(cc, ln)];          // W0 h0-rows
    } else if (i < N0+N1) {
      int idx = i - N0;
      int cc = idx >> 15; int rem = idx & 32767;
      int kb = rem >> 8; int ln = (rem >> 2) & 63; int j = idx & 3;
      int k2 = kb*4 + j;                                  // 0..255 h0n, 256..511 h1
      wp1[idx] = W1[k2*FH + gcol(cc, ln)];
    } else if (i < N0+N1+N2) {
      int l = i - N0 - N1;
      int v = l >> 8, k = l & 255;
      dwT[l] = dW[k*V_ + v];
    } else {
      int cc2 = i - N0 - N1 - N2;
      b1p[cc2] = b1[gcol(cc2>>6, cc2&63)];
    }
  }
}

__global__ void prep_tok(const float* __restrict__ cemb, const float* __restrict__ W0,
                         float* __restrict__ ws) {
  __shared__ float ce[E_];
  float* TP = ws + OFF_TP;
  int v = blockIdx.x >> 2, q = blockIdx.x & 3;
  int tid = threadIdx.x;
  if (tid < E_) ce[tid] = cemb[v*E_ + tid];
  __syncthreads();
  int ccol = q*256 + tid;
  int G = gcol(ccol>>6, ccol&63);
  float acc = 0.f;
  for (int e = 0; e < E_; ++e) acc = fmaf(ce[e], W0[e*FH + G], acc);
  TP[v*FH + ccol] = acc;
}

__global__ void prep_clus(const int* __restrict__ clus, const float* __restrict__ clemb,
                          const float* __restrict__ W0, const float* __restrict__ b0,
                          float* __restrict__ ws) {
  __shared__ float ce[H_];
  float* CP = ws + OFF_CP;
  int b = blockIdx.x >> 2, q = blockIdx.x & 3;
  int tid = threadIdx.x;
  int cl = clus[b];
  ce[tid] = clemb[(long long)cl*H_ + tid];
  __syncthreads();
  int ccol = q*256 + tid;
  int G = gcol(ccol>>6, ccol&63);
  float acc = b0[G];
  for (int e = 0; e < H_; ++e) acc = fmaf(ce[e], W0[(E_+e)*FH + G], acc);
  CP[b*FH + ccol] = acc;
}

// ============ sync & staging primitives ============

__device__ __forceinline__ void st64(float* p, float a, float b) {
  float2 t; t.x = a; t.y = b;
  __hip_atomic_store((unsigned long long*)p, __builtin_bit_cast(unsigned long long, t),
                     __ATOMIC_RELAXED, __HIP_MEMORY_SCOPE_AGENT);
}

__device__ __forceinline__ unsigned long long ld64(const void* p) {
  return __hip_atomic_load((const unsigned long long*)p, __ATOMIC_RELAXED,
                           __HIP_MEMORY_SCOPE_AGENT);
}

// relaxed flag publish ordered by explicit vmcnt drain (no wbl2 on the path)
__device__ __forceinline__ void flag_set(unsigned* p, unsigned v) {
  asm volatile("s_waitcnt vmcnt(0)" ::: "memory");
  __hip_atomic_store(p, v, __ATOMIC_RELAXED, __HIP_MEMORY_SCOPE_AGENT);
}

// wave-0 poll; flags spread one 64B line per (c, type): fA at c*32, fB at c*32+16.
// lanes 0-31 cover the 16 fA lines, lanes 32-63 the 16 fB lines.
__device__ __forceinline__ void spinAB(const unsigned* fgrp, int lane, unsigned tgt) {
  const unsigned* p = fgrp + (lane & 15)*32 + ((lane >> 5) << 4);
  unsigned v = __hip_atomic_load(p, __ATOMIC_RELAXED, __HIP_MEMORY_SCOPE_AGENT);
  while (!__all((int)(v >= tgt))) {
    __builtin_amdgcn_s_sleep(4);
    v = __hip_atomic_load(p, __ATOMIC_RELAXED, __HIP_MEMORY_SCOPE_AGENT);
  }
}

// epilogue: fB lines only
__device__ __forceinline__ void spinB(const unsigned* fgrp, int lane, unsigned tgt) {
  const unsigned* p = fgrp + (lane & 15)*32 + 16;
  unsigned v = __hip_atomic_load(p, __ATOMIC_RELAXED, __HIP_MEMORY_SCOPE_AGENT);
  while (!__all((int)(v >= tgt))) {
    __builtin_amdgcn_s_sleep(4);
    v = __hip_atomic_load(p, __ATOMIC_RELAXED, __HIP_MEMORY_SCOPE_AGENT);
  }
}

__device__ __forceinline__ void lstm_gate(const f4 z, float& cc, float& hh, const bool upd) {
  float ci = sigm(z.x);
  float cj = tanh_(z.y);
  float cf = sigm(z.z + 1.f);
  float co = sigm(z.w);
  float cn = fmaf(cc, cf, ci*cj);
  float hn = tanh_(cn)*co;
  if (upd) { cc = cn; hh = hn; }
}

// ============ main persistent kernel ============
//
// Merged single-exchange schedule (GROUPS=32, 512 WGs, 2 blocks/CU):
//   buf(t&1) holds {H0(t), H1(t-1)}, flags fA,fB >= t+1 when complete.
// Row-pair permutation r' = 2q+m (actual row = q+4m): gate lane (q,gu)
// publishes its 2 rows as ONE contiguous 8B store; a wave's publish is a
// dense 512B block, and global layout == LDS layout (pure memcpy staging).
// Each wave stages ONLY its own 64-k slice (matvec + proj consume only
// k in [wv*64, wv*64+64)) -> staging is wave-private, no barrier needed.
// 2 barriers per step. Flags: one 64B line per (c,type) to kill the
// 16-writer same-line serialization at the coherence point.

__global__ __launch_bounds__(256, 2) void lstm_persist(
    const int* __restrict__ toks, const int* __restrict__ lens,
    const float* __restrict__ decB, float* __restrict__ ws, float* __restrict__ out)
{
  const int blk  = blockIdx.x;
  const int grp  = ((blk & 7) << 2) | (blk >> 7);   // 0..31, same-XCD group
  const int c    = (blk >> 3) & 15;                  // column-WG 0..15
  const int tid  = threadIdx.x;
  const int lane = tid & 63;
  const int wv   = tid >> 6;
  const int cof  = c*64;

  float* ht0 = ws + OFF_HT0;
  float* ht1 = ws + OFF_HT1;
  unsigned* fgrp = (unsigned*)(ws + OFF_BAR) + grp*1024;
  const float* TP   = ws + OFF_TP;
  const float* CP   = ws + OFF_CP;
  const float* wp0c = ws + OFF_WP0 + c*(64*64*4);
  const float* wp1c = ws + OFF_WP1 + c*(128*64*4);
  const float* dwT  = ws + OFF_DWT;
  const float* b1p  = ws + OFF_B1;

  __shared__ __align__(16) float h0s[2048];     // [256k][8 r'], wave-sliced
  __shared__ __align__(16) float h1s[2048];
  __shared__ __align__(16) float za[4][8][64];  // z0 partials [wave][r'][col]
  __shared__ __align__(16) float zb[4][8][64];  // z1 partials
  __shared__ float ldsW[8][260];                // decoderW slice [v][k], padded
  __shared__ float pred[4][64];                 // projection partials [kslice][pm*8+pv]

  // stage decoder weight slice (v = c*8 .. c*8+7)
  for (int i = tid; i < 8*H_; i += 256)
    ldsW[i>>8][i&255] = dwT[(c*8 + (i>>8))*H_ + (i&255)];

  // ---- group max length (all lanes) ----
  int Lg = lens[grp*RPG + (lane & 7)];
  Lg = max(Lg, __shfl_xor(Lg, 1));
  Lg = max(Lg, __shfl_xor(Lg, 2));
  Lg = max(Lg, __shfl_xor(Lg, 4));

  // ---- gate-lane constants (wave0 = layer0, wave1 = layer1) ----
  const int gu = lane & 15, q = lane >> 4;   // unit 0..15, q 0..3 (rows q, q+4)
  const int rowA = grp*RPG + q, rowB = grp*RPG + q + 4;
  const int lenA = lens[rowA], lenB = lens[rowB];
  const int* tokApt = toks + rowA*T_;
  const int* tokBpt = toks + rowB*T_;
  const f4 cpA = *(const f4*)(CP + rowA*FH + cof + gu*4);
  const f4 cpB = *(const f4*)(CP + rowB*FH + cof + gu*4);
  const f4 b1v = *(const f4*)(b1p + cof + gu*4);
  const int puboff = grp*HTG + (c*16 + gu)*8 + q*2;   // r' = 2q (+1)
  float c0A = 0.f, h0A = 0.f, c0B = 0.f, h0B = 0.f;   // wave0 L0 state
  float c1A = 0.f, h1A = 0.f, c1B = 0.f, h1B = 0.f;   // wave1 L1 state

  // ---- projection constants ----
  const int pm = lane >> 3, pv = lane & 7;            // row 0..7, vocab-col 0..7
  const int prm = (pm < 4) ? pm*2 : (pm-4)*2 + 1;     // r' of row pm
  const int plen = lens[grp*RPG + pm];
  const float decb = decB[c*8 + pv];
  float* outp = out + (size_t)(grp*RPG + pm)*T_*V_ + c*8 + pv;

  __syncthreads();   // ldsW staged

  // ---- prologue: H0(0) from TP+CP; H1(-1)=0 via pre-zeroed ws ----
  if (wv == 0) {
    f4 zAv = *(const f4*)(TP + tokApt[0]*FH + cof + gu*4) + cpA;
    f4 zBv = *(const f4*)(TP + tokBpt[0]*FH + cof + gu*4) + cpB;
    lstm_gate(zAv, c0A, h0A, 0 < lenA);
    lstm_gate(zBv, c0B, h0B, 0 < lenB);
    st64(ht0 + puboff, h0A, h0B);                 // buf0
    if (lane == 0) flag_set(fgrp + c*32, 1u);
  } else if (wv == 1) {
    if (lane == 0) flag_set(fgrp + c*32 + 16, 1u);  // h1 buf0 pre-zeroed
  }

  for (int t = 0; t < Lg; ++t) {
    const int buf = t & 1;

    // TP prefetch for next-step z0 (in flight across the spin)
    f4 tpA = {0,0,0,0}, tpB = {0,0,0,0};
    if (wv == 0 && t + 1 < Lg) {
      tpA = *(const f4*)(TP + tokApt[t+1]*FH + cof + gu*4);
      tpB = *(const f4*)(TP + tokBpt[t+1]*FH + cof + gu*4);
    }

    // ---- single wait per step: {H0(t), H1(t-1)} both ready ----
    if (wv == 0) spinAB(fgrp, lane, (unsigned)(t + 1));
    __syncthreads();                                   // (1)
    __atomic_signal_fence(__ATOMIC_SEQ_CST);

    // ---- per-wave stage of OWN 64-k slice (wave-private: no barrier) ----
    {
      const float* s0 = ht0 + buf*GST + grp*HTG + wv*512 + lane*8;
      const float* s1 = ht1 + buf*GST + grp*HTG + wv*512 + lane*8;
      unsigned long long a0 = ld64(s0),   a1 = ld64(s0+2);
      unsigned long long a2 = ld64(s0+4), a3 = ld64(s0+6);
      unsigned long long b0 = ld64(s1),   b1 = ld64(s1+2);
      unsigned long long b2 = ld64(s1+4), b3 = ld64(s1+6);
      float* d0 = h0s + wv*512 + lane*8;
      float* d1 = h1s + wv*512 + lane*8;
      *(unsigned long long*)(d0)   = a0; *(unsigned long long*)(d0+2) = a1;
      *(unsigned long long*)(d0+4) = a2; *(unsigned long long*)(d0+6) = a3;
      *(unsigned long long*)(d1)   = b0; *(unsigned long long*)(d1+2) = b1;
      *(unsigned long long*)(d1+4) = b2; *(unsigned long long*)(d1+6) = b3;
    }

    // ---- fused matvec over this wave's k-window:
    //      A0 = W0h*h0; A1 = W1lo*h0 + W1up*h1 (rows in r' order) ----
    f4 A0l = {0,0,0,0}, A0h = {0,0,0,0}, A1l = {0,0,0,0}, A1h = {0,0,0,0};
    #pragma unroll 2
    for (int b = 0; b < 16; ++b) {
      const int kb = wv*16 + b;
      const f4 w0 = *(const f4*)(wp0c + kb*256 + lane*4);
      const f4 wl = *(const f4*)(wp1c + kb*256 + lane*4);
      const f4 wu = *(const f4*)(wp1c + (64 + kb)*256 + lane*4);
      #pragma unroll
      for (int j = 0; j < 4; ++j) {
        const int k = kb*4 + j;
        const float* hb0 = h0s + k*8;
        const float* hb1 = h1s + k*8;
        const f4 h0lo = *(const f4*)(hb0);
        const f4 h0hi = *(const f4*)(hb0 + 4);
        const f4 h1lo = *(const f4*)(hb1);
        const f4 h1hi = *(const f4*)(hb1 + 4);
        const float w0j = w0[j], wlj = wl[j], wuj = wu[j];
        A0l += w0j * h0lo;  A0h += w0j * h0hi;
        A1l += wlj * h0lo + wuj * h1lo;
        A1h += wlj * h0hi + wuj * h1hi;
      }
    }

    // ---- projection partial over this wave's k-window (h1 = H1(t-1)) ----
    float pacc = 0.f;
    {
      const int kq = wv*64;
      #pragma unroll 4
      for (int k2 = 0; k2 < 64; k2 += 4) {
        const f4 w4 = *(const f4*)&ldsW[pv][kq + k2];
        pacc = fmaf(h1s[(kq+k2  )*8 + prm], w4.x, pacc);
        pacc = fmaf(h1s[(kq+k2+1)*8 + prm], w4.y, pacc);
        pacc = fmaf(h1s[(kq+k2+2)*8 + prm], w4.z, pacc);
        pacc = fmaf(h1s[(kq+k2+3)*8 + prm], w4.w, pacc);
      }
    }

    #pragma unroll
    for (int r = 0; r < 4; ++r) {
      za[wv][r][lane]     = A0l[r];
      za[wv][4 + r][lane] = A0h[r];
      zb[wv][r][lane]     = A1l[r];
      zb[wv][4 + r][lane] = A1h[r];
    }
    pred[wv][lane] = pacc;
    __syncthreads();                                   // (2)

    if (wv == 0) {
      // gates L0 -> H0(t+1), publish to buf^1   (rows q -> r'=2q, q+4 -> 2q+1)
      if (t + 1 < Lg) {
        f4 zA = *(const f4*)&za[0][q*2][gu*4];
        zA += *(const f4*)&za[1][q*2][gu*4];
        zA += *(const f4*)&za[2][q*2][gu*4];
        zA += *(const f4*)&za[3][q*2][gu*4];
        f4 zB = *(const f4*)&za[0][q*2+1][gu*4];
        zB += *(const f4*)&za[1][q*2+1][gu*4];
        zB += *(const f4*)&za[2][q*2+1][gu*4];
        zB += *(const f4*)&za[3][q*2+1][gu*4];
        zA += tpA + cpA;
        zB += tpB + cpB;
        lstm_gate(zA, c0A, h0A, (t+1) < lenA);
        lstm_gate(zB, c0B, h0B, (t+1) < lenB);
        st64(ht0 + (buf^1)*GST + puboff, h0A, h0B);
        if (lane == 0) flag_set(fgrp + c*32, (unsigned)(t + 2));
      }
    } else if (wv == 1) {
      // gates L1 -> H1(t), publish to buf^1
      f4 zA = *(const f4*)&zb[0][q*2][gu*4];
      zA += *(const f4*)&zb[1][q*2][gu*4];
      zA += *(const f4*)&zb[2][q*2][gu*4];
      zA += *(const f4*)&zb[3][q*2][gu*4];
      f4 zB = *(const f4*)&zb[0][q*2+1][gu*4];
      zB += *(const f4*)&zb[1][q*2+1][gu*4];
      zB += *(const f4*)&zb[2][q*2+1][gu*4];
      zB += *(const f4*)&zb[3][q*2+1][gu*4];
      zA += b1v;
      zB += b1v;
      lstm_gate(zA, c1A, h1A, t < lenA);
      lstm_gate(zB, c1B, h1B, t < lenB);
      st64(ht1 + (buf^1)*GST + puboff, h1A, h1B);
      if (lane == 0) flag_set(fgrp + c*32 + 16, (unsigned)(t + 2));
    } else if (wv == 2) {
      // out(t-1) from this iteration's pred (computed from H1(t-1))
      if (t > 0) {
        float tot = pred[0][lane] + pred[1][lane] + pred[2][lane] + pred[3][lane] + decb;
        if (t - 1 < plen) outp[(size_t)(t-1)*V_] = tot;
      }
    }
  }

  // ---- epilogue: out(Lg-1) from H1(Lg-1) in buf (Lg&1), fB reaches Lg+1 ----
  if (wv == 0) spinB(fgrp, lane, (unsigned)(Lg + 1));
  __syncthreads();
  __atomic_signal_fence(__ATOMIC_SEQ_CST);
  {
    const float* s1 = ht1 + (size_t)(Lg & 1)*GST + grp*HTG + wv*512 + lane*8;
    unsigned long long b0 = ld64(s1),   b1 = ld64(s1+2);
    unsigned long long b2 = ld64(s1+4), b3 = ld64(s1+6);
    float* d1 = h1s + wv*512 + lane*8;
    *(unsigned long long*)(d1)   = b0; *(unsigned long long*)(d1+2) = b1;
    *(unsigned long long*)(d1+4) = b2; *(unsigned long long*)(d1+6) = b3;
  }
  {
    float pacc = 0.f;
    const int kq = wv*64;
    #pragma unroll 4
    for (int k2 = 0; k2 < 64; k2 += 4) {
      const f4 w4 = *(const f4*)&ldsW[pv][kq + k2];
      pacc = fmaf(h1s[(kq+k2  )*8 + prm], w4.x, pacc);
      pacc = fmaf(h1s[(kq+k2+1)*8 + prm], w4.y, pacc);
      pacc = fmaf(h1s[(kq+k2+2)*8 + prm], w4.z, pacc);
      pacc = fmaf(h1s[(kq+k2+3)*8 + prm], w4.w, pacc);
    }
    pred[wv][lane] = pacc;
  }
  __syncthreads();
  if (wv == 2) {
    float tot = pred[0][lane] + pred[1][lane] + pred[2][lane] + pred[3][lane] + decb;
    if (Lg - 1 < plen) outp[(size_t)(Lg-1)*V_] = tot;
  }
}

// ============ launch ============

extern "C" void kernel_launch(void* const* d_in, const int* in_sizes, int n_in,
                              void* d_out, int out_size, void* d_ws, size_t ws_size,
                              hipStream_t stream) {
  const int*   toks  = (const int*)d_in[0];
  const int*   lens  = (const int*)d_in[1];
  const int*   clus  = (const int*)d_in[2];
  const float* cemb  = (const float*)d_in[3];
  const float* clemb = (const float*)d_in[4];
  const float* W0    = (const float*)d_in[5];
  const float* b0    = (const float*)d_in[6];
  const float* W1    = (const float*)d_in[7];
  const float* b1    = (const float*)d_in[8];
  const float* dW    = (const float*)d_in[9];
  const float* decB  = (const float*)d_in[10];
  float* out = (float*)d_out;
  float* ws  = (float*)d_ws;

  // zero output (masked positions must be exactly 0), h buffers (H1(-1)=0),
  // and the flag block
  hipMemsetAsync(out, 0, (size_t)B_*T_*V_*sizeof(float), stream);
  hipMemsetAsync(ws, 0, (size_t)(OFF_BAR + BARSZ)*sizeof(float), stream);

  prep_pack<<<1024, 256, 0, stream>>>(W0, W1, dW, b1, ws);
  prep_tok <<<V_*4, 256, 0, stream>>>(cemb, W0, ws);
  prep_clus<<<B_*4, 256, 0, stream>>>(clus, clemb, W0, b0, ws);
  lstm_persist<<<NWG, 256, 0, stream>>>(toks, lens, decB, ws, out);
}